// Round 7
// baseline (146.858 us; speedup 1.0000x reference)
//
#include <hip/hip_runtime.h>
#include <hip/hip_bf16.h>

typedef __attribute__((ext_vector_type(4))) float f32x4;
typedef __attribute__((ext_vector_type(2))) long longx2;   // 16 B load

#define N_ROWS 8192
#define B_HALF 4096
#define EXP2C 2.885390081777927f   // 2*log2(e): exp(2S) = exp2(S*EXP2C)

// ws layout (bytes)
#define WS_ZN       0                    // fp8 frag-major [512 groups][4096 B] = 2 MB
#define WS_ROWACC   2097152              // float[8192]  sum_j exp(2 S_ij)
#define WS_POS      2129920              // float[8192]  raw S_pos
#define WS_DIAG     2162688              // float[8192]  exp2(S_ii*EXP2C)
#define WS_ACC      2195456              // float final accum
#define WS_CNT      2195460              // uint  block counter

__device__ __forceinline__ float fexp2(float x) {
#if __has_builtin(__builtin_amdgcn_exp2f)
    return __builtin_amdgcn_exp2f(x);
#else
    return exp2f(x);
#endif
}

__device__ __forceinline__ void async_copy16(const void* g, void* l) {
    __builtin_amdgcn_global_load_lds(
        (const __attribute__((address_space(1))) unsigned int*)g,
        (__attribute__((address_space(3))) unsigned int*)l,
        16, 0, 0);
}

// ---------------- Phase 1: normalize -> fp8, FRAGMENT-MAJOR layout -----------
// (unchanged from R6; layout validated absmax 0.0)
// element k of row r: granule (group g=r>>4, t4=k>>6, r&15, q=(k>>3)&3) at
//   addr = g*4096 + t4*1024 + (r&15)*64 + q*16 + ((k>>5)&1)*8 + (k&7)
__global__ __launch_bounds__(256) void normalize_k(
    const float* __restrict__ z_orig, const float* __restrict__ z_aug,
    unsigned char* __restrict__ zn, float* __restrict__ rowAcc,
    float* __restrict__ accum, unsigned int* __restrict__ cnt)
{
    if (blockIdx.x == 0 && threadIdx.x == 0) { *accum = 0.0f; *cnt = 0u; }
    const int row  = blockIdx.x * 4 + (threadIdx.x >> 6);
    const int lane = threadIdx.x & 63;
    if (lane == 0) rowAcc[row] = 0.0f;       // zeroed before tile_k (stream order)
    const float* src = (row < B_HALF) ? (z_aug  + (size_t)row * 256)
                                      : (z_orig + (size_t)(row - B_HALF) * 256);
    float4 v = ((const float4*)src)[lane];
    float ss = v.x*v.x + v.y*v.y + v.z*v.z + v.w*v.w;
    #pragma unroll
    for (int m = 1; m < 64; m <<= 1) ss += __shfl_xor(ss, m);
    float inv = 1.0f / fmaxf(sqrtf(ss), 1e-8f);
    int pk = 0;
    pk = __builtin_amdgcn_cvt_pk_fp8_f32(v.x * inv, v.y * inv, pk, false);
    pk = __builtin_amdgcn_cvt_pk_fp8_f32(v.z * inv, v.w * inv, pk, true);
    const int addr = ((row >> 4) << 12) | ((lane >> 4) << 10) | ((row & 15) << 6)
                   | (((lane >> 1) & 3) << 4) | (((lane >> 3) & 1) << 3)
                   | ((lane & 1) << 2);
    *(int*)(zn + addr) = pk;
}

// ---------------- Phase 2: persistent strip-blocks ---------------------------
// Block (rb, seg): A-strip rb (32 KB) staged to LDS ONCE; sweep tiles
// cb = rb+seg, rb+seg+8, ...  Wave w computes cols [w*32, w*32+32) x 128 rows.
// B frags global->VGPR, double-buffered across tiles; diag tile reads B from
// LDS. One barrier per block lifetime.
__global__ __launch_bounds__(256, 2) void tile_k(
    const unsigned char* __restrict__ zn,
    float* __restrict__ rowAcc,         // [8192] += sum_j exp(2 S_ij)
    float* __restrict__ posv,           // [8192] raw S_pos
    float* __restrict__ diagE)          // [8192] exp2(S_ii*EXP2C)
{
    __shared__ unsigned char As[32768];

    const int rb  = blockIdx.x >> 3;
    const int seg = blockIdx.x & 7;
    if (rb + seg > 63) return;               // block-uniform, before any barrier

    const int t      = threadIdx.x;
    const int lane   = t & 63;
    const int w      = t >> 6;
    const int lane15 = lane & 15;
    const int quad   = lane >> 4;
    const int rowBase = rb * 128;
    const int laneOff = lane15 * 64 + quad * 16;

    // tile list
    int cbs[8]; int nt = 0;
    for (int cb = rb + seg; cb <= 63; cb += 8) cbs[nt++] = cb;

    // stage A strip (layout-identical 32 KB copy)
    const unsigned char* gA = zn + (size_t)rb * 32768;
    {
        const int off = w * 1024 + lane * 16;
        #pragma unroll
        for (int s = 0; s < 8; ++s)
            async_copy16(gA + s * 4096 + off, As + s * 4096 + w * 1024);
    }

    longx2 bcur[8], bnxt[8];
    // pre-issue first tile's B (global) if it isn't the diagonal tile
    if (cbs[0] != rb) {
        const unsigned char* gB = zn + (size_t)(cbs[0] * 8 + 2 * w) * 4096 + laneOff;
        #pragma unroll
        for (int nj = 0; nj < 2; ++nj)
            #pragma unroll
            for (int t4 = 0; t4 < 4; ++t4)
                bcur[nj * 4 + t4] = *(const longx2*)(gB + nj * 4096 + t4 * 1024);
    }

    __syncthreads();                          // A staged (drains all vmcnt)

    if (cbs[0] == rb) {                       // diag tile: B = A from LDS
        #pragma unroll
        for (int nj = 0; nj < 2; ++nj)
            #pragma unroll
            for (int t4 = 0; t4 < 4; ++t4)
                bcur[nj * 4 + t4] = *(const longx2*)(As + (2 * w + nj) * 4096
                                                     + t4 * 1024 + laneOff);
    }

    const bool diagLane = (lane15 >> 2) == quad;
    const int  rsel = lane15 & 3;

    #pragma unroll 1
    for (int ti = 0; ti < nt; ++ti) {
        const int cb = cbs[ti];

        // prefetch next tile's B (never the diagonal: cb strictly increases)
        if (ti + 1 < nt) {
            const unsigned char* gB = zn + (size_t)(cbs[ti + 1] * 8 + 2 * w) * 4096
                                    + laneOff;
            #pragma unroll
            for (int nj = 0; nj < 2; ++nj)
                #pragma unroll
                for (int t4 = 0; t4 < 4; ++t4)
                    bnxt[nj * 4 + t4] = *(const longx2*)(gB + nj * 4096 + t4 * 1024);
        }

        f32x4 acc[8][2];
        #pragma unroll
        for (int mi = 0; mi < 8; ++mi)
            #pragma unroll
            for (int nj = 0; nj < 2; ++nj)
                acc[mi][nj] = (f32x4){0.f, 0.f, 0.f, 0.f};

        #pragma unroll
        for (int t4 = 0; t4 < 4; ++t4) {
            longx2 af[8];
            #pragma unroll
            for (int mi = 0; mi < 8; ++mi)
                af[mi] = *(const longx2*)(As + mi * 4096 + t4 * 1024 + laneOff);
            #pragma unroll
            for (int mi = 0; mi < 8; ++mi)
                #pragma unroll
                for (int nj = 0; nj < 2; ++nj)
                    acc[mi][nj] = __builtin_amdgcn_mfma_f32_16x16x32_fp8_fp8(
                                      af[mi].x, bcur[nj * 4 + t4].x, acc[mi][nj], 0, 0, 0);
            #pragma unroll
            for (int mi = 0; mi < 8; ++mi)
                #pragma unroll
                for (int nj = 0; nj < 2; ++nj)
                    acc[mi][nj] = __builtin_amdgcn_mfma_f32_16x16x32_fp8_fp8(
                                      af[mi].y, bcur[nj * 4 + t4].y, acc[mi][nj], 0, 0, 0);
        }

        // ---- epilogue ----
        // C/D layout: m-row = quad*4 + reg, n-col = lane15 (validated r1-r6).
        // frag (mi,nj): row = rowBase + mi*16 + quad*4 + r,
        //               col = cb*128 + w*32 + nj*16 + lane15
        if (cb == rb && diagLane) {
            #pragma unroll
            for (int nj = 0; nj < 2; ++nj) {
                const int mi = 2 * w + nj;
                diagE[rowBase + mi * 16 + lane15] = fexp2(acc[mi][nj][rsel] * EXP2C);
            }
        }
        if (cb == rb + 32 && diagLane) {      // positive-pair diagonal
            #pragma unroll
            for (int nj = 0; nj < 2; ++nj) {
                const int mi = 2 * w + nj;
                float v = acc[mi][nj][rsel];
                posv[rowBase + mi * 16 + lane15] = v;
                posv[rowBase + mi * 16 + lane15 + B_HALF] = v;
            }
        }

        #pragma unroll
        for (int mi = 0; mi < 8; ++mi)
            #pragma unroll
            for (int nj = 0; nj < 2; ++nj)
                #pragma unroll
                for (int r = 0; r < 4; ++r)
                    acc[mi][nj][r] = fexp2(acc[mi][nj][r] * EXP2C);

        // row sums over this wave's 32 cols
        #pragma unroll
        for (int mi = 0; mi < 8; ++mi)
            #pragma unroll
            for (int r = 0; r < 4; ++r) {
                float s = acc[mi][0][r] + acc[mi][1][r];
                s += __shfl_xor(s, 1);
                s += __shfl_xor(s, 2);
                s += __shfl_xor(s, 4);
                s += __shfl_xor(s, 8);
                if (lane15 == 0)
                    atomicAdd(&rowAcc[rowBase + mi * 16 + quad * 4 + r], s);
            }

        // col sums over all 128 rows (off-diagonal tiles only)
        if (cb != rb) {
            #pragma unroll
            for (int nj = 0; nj < 2; ++nj) {
                float s = 0.0f;
                #pragma unroll
                for (int mi = 0; mi < 8; ++mi)
                    s += acc[mi][nj][0] + acc[mi][nj][1]
                       + acc[mi][nj][2] + acc[mi][nj][3];
                s += __shfl_xor(s, 16);
                s += __shfl_xor(s, 32);
                if (quad == 0)
                    atomicAdd(&rowAcc[cb * 128 + w * 32 + nj * 16 + lane15], s);
            }
        }

        // rotate double buffer
        #pragma unroll
        for (int i = 0; i < 8; ++i) bcur[i] = bnxt[i];
    }
}

// ---------------- Phase 3: per-row loss + grid reduction (last block) --------
__global__ __launch_bounds__(256) void loss_k(
    const float* __restrict__ rowAcc, const float* __restrict__ posv,
    const float* __restrict__ diagE, float* __restrict__ accum,
    unsigned int* __restrict__ cnt, float* __restrict__ out)
{
    const int i = blockIdx.x * 256 + threadIdx.x;
    float s = rowAcc[i] - diagE[i];             // drop main-diagonal term
    float loss = __logf(s) - 2.0f * posv[i];    // logits = 2*S (tau = 0.5)

    #pragma unroll
    for (int m = 1; m < 64; m <<= 1) loss += __shfl_xor(loss, m);
    __shared__ float red[4];
    if ((threadIdx.x & 63) == 0) red[threadIdx.x >> 6] = loss;
    __syncthreads();
    if (threadIdx.x == 0) {
        float bs = red[0] + red[1] + red[2] + red[3];
        atomicAdd(accum, bs);
        __threadfence();
        unsigned int old = atomicAdd(cnt, 1u);
        if (old == 31u) {                       // last of 32 blocks
            __threadfence();
            float total = atomicAdd(accum, 0.0f);
            out[0] = total * (1.0f / (float)N_ROWS);
        }
    }
}

extern "C" void kernel_launch(void* const* d_in, const int* in_sizes, int n_in,
                              void* d_out, int out_size, void* d_ws, size_t ws_size,
                              hipStream_t stream) {
    const float* z_orig = (const float*)d_in[0];
    const float* z_aug  = (const float*)d_in[1];
    char* ws = (char*)d_ws;
    unsigned char* zn   = (unsigned char*)(ws + WS_ZN);
    float* rowAcc       = (float*)(ws + WS_ROWACC);
    float* posv         = (float*)(ws + WS_POS);
    float* diagE        = (float*)(ws + WS_DIAG);
    float* accum        = (float*)(ws + WS_ACC);
    unsigned int* cnt   = (unsigned int*)(ws + WS_CNT);

    normalize_k<<<N_ROWS / 4, 256, 0, stream>>>(z_orig, z_aug, zn, rowAcc, accum, cnt);
    tile_k<<<512, 256, 0, stream>>>(zn, rowAcc, posv, diagE);
    loss_k<<<N_ROWS / 256, 256, 0, stream>>>(rowAcc, posv, diagE, accum, cnt,
                                             (float*)d_out);
}